// Round 10
// baseline (615.890 us; speedup 1.0000x reference)
//
#include <hip/hip_runtime.h>
#include <hip/hip_bf16.h>

// SimVQ: x[8,2048,512] f32, codebook[4096,512] f32, W[512,512] f32
// out (f32 flat): quantized_out[16384*512] | indices[16384] (as f32) | commit_loss[1]
//
// Round 10: k_dist = 128 rows x 512 codes per block (4 col-tiles, flat 64-step
// pipelined loop), double-buffered LDS (32 KB) + counted s_waitcnt vmcnt(4)
// (T3+T4) at 4 blocks/CU. t2 partials transposed to row-major [row][64] so
// k_rot phase-1 reads coalesce. 1-leg bf16 GEMM + top-4 fp64 rescue unchanged.

typedef unsigned short ushort_t;
typedef __attribute__((ext_vector_type(8))) short bf16x8;
typedef __attribute__((ext_vector_type(4))) float f32x4;

constexpr int D  = 512;
constexpr int C  = 4096;
constexpr int NR = 16384;
constexpr int NSL = 64;             // partial slices per row (row-major)
constexpr float DELTA = 1.0f;       // top-4 fp64 rescue threshold (~12 sigma)

__device__ __forceinline__ ushort_t f2bf(float v) {
  __hip_bfloat16 h = __float2bfloat16(v);
  return *reinterpret_cast<ushort_t*>(&h);
}

__device__ __forceinline__ void gld16(void* lds, const void* g) {
  __builtin_amdgcn_global_load_lds(
      (const __attribute__((address_space(1))) unsigned int*)g,
      (__attribute__((address_space(3))) unsigned int*)lds, 16, 0, 0);
}

__device__ __forceinline__ bool lexlt(float v, int i, float ov, int oi) {
  return v < ov || (v == ov && i < oi);
}

__device__ __forceinline__ void top2_merge(float& v1, int& i1, float& v2, int& i2,
                                           float ov1, int oi1, float ov2, int oi2) {
  if (lexlt(ov1, oi1, v1, i1)) {
    float nv2; int ni2;
    if (lexlt(v1, i1, ov2, oi2)) { nv2 = v1; ni2 = i1; }
    else { nv2 = ov2; ni2 = oi2; }
    v2 = nv2; i2 = ni2; v1 = ov1; i1 = oi1;
  } else {
    if (lexlt(ov1, oi1, v2, i2)) { v2 = ov1; i2 = oi1; }
  }
}

// ---------------- K1: implicit = codebook @ W^T, fused qnorm2 + bf16 hi ----------------
__global__ __launch_bounds__(256) void k_implicit(
    const float* __restrict__ cb, const float* __restrict__ W,
    float* __restrict__ imp, float* __restrict__ qnorm2,
    ushort_t* __restrict__ ih) {
  __shared__ float As[16][65];
  __shared__ float Bs[16][65];
  const int c0 = blockIdx.x * 64;
  const int j0 = blockIdx.y * 64;
  const int tid = threadIdx.x;
  const int tr = tid >> 4, tc = tid & 15;
  const int lm = tid >> 2;
  const int lq = (tid & 3) << 2;
  float acc[4][4] = {{0.f}};
  for (int kk = 0; kk < D; kk += 16) {
    __syncthreads();
    float4 av = *(const float4*)(cb + (size_t)(c0 + lm) * D + kk + lq);
    float4 bv = *(const float4*)(W  + (size_t)(j0 + lm) * D + kk + lq);
    As[lq + 0][lm] = av.x; As[lq + 1][lm] = av.y; As[lq + 2][lm] = av.z; As[lq + 3][lm] = av.w;
    Bs[lq + 0][lm] = bv.x; Bs[lq + 1][lm] = bv.y; Bs[lq + 2][lm] = bv.z; Bs[lq + 3][lm] = bv.w;
    __syncthreads();
#pragma unroll
    for (int k = 0; k < 16; ++k) {
      float a[4], b[4];
#pragma unroll
      for (int i = 0; i < 4; ++i) a[i] = As[k][tr * 4 + i];
#pragma unroll
      for (int j = 0; j < 4; ++j) b[j] = Bs[k][tc * 4 + j];
#pragma unroll
      for (int i = 0; i < 4; ++i)
#pragma unroll
        for (int j = 0; j < 4; ++j) acc[i][j] = fmaf(a[i], b[j], acc[i][j]);
    }
  }
#pragma unroll
  for (int i = 0; i < 4; ++i) {
    const int row = c0 + tr * 4 + i;
    float sq = 0.f;
#pragma unroll
    for (int j = 0; j < 4; ++j) {
      const float v = acc[i][j];
      const size_t off = (size_t)row * D + j0 + tc * 4 + j;
      imp[off] = v;
      ih[off] = f2bf(v);
      sq = fmaf(v, v, sq);
    }
#pragma unroll
    for (int m = 1; m < 16; m <<= 1) sq += __shfl_xor(sq, m, 64);
    if (tc == 0) atomicAdd(&qnorm2[row], sq);
  }
}

// ---------------- K1b: x -> xh bf16 ----------------
__global__ __launch_bounds__(256) void k_cvt(const float* __restrict__ x,
                                             ushort_t* __restrict__ xh) {
  const size_t i = ((size_t)blockIdx.x * 256 + threadIdx.x) * 4;
  float4 v = *(const float4*)(x + i);
  ushort4 h;
  h.x = f2bf(v.x); h.y = f2bf(v.y); h.z = f2bf(v.z); h.w = f2bf(v.w);
  *(ushort4*)(xh + i) = h;
}

// ---------------- K2: 1-leg MFMA distance + fused TOP-2 argmin ----------------
// grid (NR/128, C/512) = (128, 8), 256 threads (4 waves, 2x2).
// Block: 128 rows x 512 codes = 4 col-tiles; flat 64-step loop, LDS dbuf
// (2x16 KB), counted vmcnt(4), conflict-free XOR swizzle.
__global__ __launch_bounds__(256, 4) void k_dist(
    const ushort_t* __restrict__ xh, const ushort_t* __restrict__ ih,
    const float* __restrict__ qnorm2,
    float2* __restrict__ t2v, int2* __restrict__ t2i) {
  __shared__ ushort_t Ah[2][4096], Bh[2][4096];
  const int r0  = blockIdx.x * 128;
  const int cb0 = blockIdx.y * 512;   // 4 col-tiles of 128
  const int t = threadIdx.x;
  const int wid = t >> 6, lane = t & 63;
  const int wr = wid >> 1, wc = wid & 1;

  const int srow = t >> 2;            // staging row 0..63
  // pre-swizzled source chunk: LDS[row][c] = G[row][c ^ ((row>>1)&3)]
  const int koff = (((t & 3) ^ ((t >> 3) & 3)) << 3);

  f32x4 acc[4][4];
#pragma unroll
  for (int m = 0; m < 4; ++m)
#pragma unroll
    for (int n = 0; n < 4; ++n) acc[m][n] = (f32x4){0.f, 0.f, 0.f, 0.f};

  // fragment reads: chunk q = lane>>4 at row R stored at q ^ ((R>>1)&3);
  // (R>>1)&3 == (lane>>1)&3 for fragment rows -> per-lane constant
  const int arow = wr * 64 + (lane & 15);
  const int brow = wc * 64 + (lane & 15);
  const int swz = (((lane >> 4) ^ ((lane >> 1) & 3)) << 3);

#define STAGE(buf, tt)                                                    \
  do {                                                                    \
    const int kk_ = ((tt) & 15) * 32;                                     \
    const int ci_ = (tt) >> 4;                                            \
    const size_t ga_ = (size_t)(r0 + srow) * D + kk_ + koff;              \
    const size_t gb_ = (size_t)(cb0 + ci_ * 128 + srow) * D + kk_ + koff; \
    char* lA_ = (char*)&Ah[buf][0] + wid * 1024;                          \
    char* lB_ = (char*)&Bh[buf][0] + wid * 1024;                          \
    gld16(lA_,        xh + ga_);                                          \
    gld16(lA_ + 4096, xh + ga_ + (size_t)64 * D);                         \
    gld16(lB_,        ih + gb_);                                          \
    gld16(lB_ + 4096, ih + gb_ + (size_t)64 * D);                         \
  } while (0)

#define COMPUTE(cur)                                                      \
  do {                                                                    \
    bf16x8 ah[4], bh[4];                                                  \
    _Pragma("unroll")                                                     \
    for (int m = 0; m < 4; ++m)                                           \
      ah[m] = *(const bf16x8*)&Ah[cur][(arow + m * 16) * 32 + swz];       \
    _Pragma("unroll")                                                     \
    for (int n = 0; n < 4; ++n)                                           \
      bh[n] = *(const bf16x8*)&Bh[cur][(brow + n * 16) * 32 + swz];       \
    _Pragma("unroll")                                                     \
    for (int m = 0; m < 4; ++m)                                           \
      _Pragma("unroll")                                                   \
      for (int n = 0; n < 4; ++n)                                         \
        acc[m][n] = __builtin_amdgcn_mfma_f32_16x16x32_bf16(ah[m], bh[n], acc[m][n], 0, 0, 0); \
  } while (0)

  STAGE(0, 0);
#pragma unroll 1
  for (int tt = 0; tt < 64; ++tt) {
    const int cur = tt & 1;
    if (tt < 63) {
      STAGE(cur ^ 1, tt + 1);
      asm volatile("s_waitcnt vmcnt(4)" ::: "memory");  // current tile landed
    } else {
      asm volatile("s_waitcnt vmcnt(0)" ::: "memory");
    }
    __builtin_amdgcn_s_barrier();          // all waves' stores visible
    __builtin_amdgcn_sched_barrier(0);
    COMPUTE(cur);
    __builtin_amdgcn_sched_barrier(0);
    __builtin_amdgcn_s_barrier();          // readers done before overwrite

    if ((tt & 15) == 15) {
      // per-ci epilogue: score = qn[c] - 2*dot; TOP-2 over this wave's 64 cols
      const int ci = tt >> 4;
      const int c0 = cb0 + ci * 128;
      int colg[4]; float qnv[4];
#pragma unroll
      for (int n = 0; n < 4; ++n) {
        colg[n] = c0 + wc * 64 + n * 16 + (lane & 15);
        qnv[n] = qnorm2[colg[n]];
      }
      const int sp2 = (blockIdx.y * 4 + ci) * 2 + wc;
#pragma unroll
      for (int m = 0; m < 4; ++m)
#pragma unroll
        for (int r = 0; r < 4; ++r) {
          float v1 = fmaf(-2.f, acc[m][0][r], qnv[0]); int i1 = colg[0];
          float v2 = 3.4e38f;                          int i2 = 0x7fffffff;
#pragma unroll
          for (int n = 1; n < 4; ++n) {
            const float s = fmaf(-2.f, acc[m][n][r], qnv[n]);
            const int   c = colg[n];
            if (lexlt(s, c, v1, i1)) { v2 = v1; i2 = i1; v1 = s; i1 = c; }
            else if (lexlt(s, c, v2, i2)) { v2 = s; i2 = c; }
          }
#pragma unroll
          for (int off = 1; off < 16; off <<= 1) {
            const float ov1 = __shfl_xor(v1, off, 64);
            const int   oi1 = __shfl_xor(i1, off, 64);
            const float ov2 = __shfl_xor(v2, off, 64);
            const int   oi2 = __shfl_xor(i2, off, 64);
            top2_merge(v1, i1, v2, i2, ov1, oi1, ov2, oi2);
          }
          if ((lane & 15) == 0) {
            const int row = r0 + wr * 64 + m * 16 + (lane >> 4) * 4 + r;
            t2v[(size_t)row * NSL + sp2] = make_float2(v1, v2);
            t2i[(size_t)row * NSL + sp2] = make_int2(i1, i2);
          }
        }
      // reset accumulators for next col-tile
#pragma unroll
      for (int m = 0; m < 4; ++m)
#pragma unroll
        for (int n = 0; n < 4; ++n) acc[m][n] = (f32x4){0.f, 0.f, 0.f, 0.f};
    }
  }
#undef COMPUTE
#undef STAGE
}

// compare-exchange ascending (lex) on named scalars
#define CE(vx, ix, vy, iy)                                        \
  do {                                                            \
    if (lexlt(vy, iy, vx, ix)) {                                  \
      float tv = vx; int ti = ix;                                 \
      vx = vy; ix = iy; vy = tv; iy = ti;                         \
    }                                                             \
  } while (0)

// ---------------- K3: top-4 merge + fp64 rescore + rotation ----------------
__global__ __launch_bounds__(256) void k_rot(
    const float* __restrict__ x, const float* __restrict__ imp,
    const float2* __restrict__ t2v, const int2* __restrict__ t2i,
    float* __restrict__ out, float* __restrict__ commit_acc) {
  const int row = blockIdx.x;
  const int tid = threadIdx.x;
  const int wid = tid >> 6, lane = tid & 63;

  __shared__ int s_ci[4];
  __shared__ int s_need, s_bi;
  __shared__ double dred[4][4];
  __shared__ float4 wsum[4];

  // phase 1: wave 0 merges the 64 per-slice top-2 into a global TOP-4
  if (wid == 0) {
    const float2 vv = t2v[(size_t)row * NSL + lane];   // coalesced row-major
    const int2   ii = t2i[(size_t)row * NSL + lane];
    float a0 = vv.x, a1 = vv.y, a2 = 3.4e38f, a3 = 3.4e38f;
    int   j0 = ii.x, j1 = ii.y, j2 = 0x7fffffff, j3 = 0x7fffffff;
#pragma unroll
    for (int off = 1; off < 64; off <<= 1) {
      const float b0 = __shfl_xor(a0, off, 64), b1 = __shfl_xor(a1, off, 64);
      const float b2 = __shfl_xor(a2, off, 64), b3 = __shfl_xor(a3, off, 64);
      const int   k0 = __shfl_xor(j0, off, 64), k1 = __shfl_xor(j1, off, 64);
      const int   k2 = __shfl_xor(j2, off, 64), k3 = __shfl_xor(j3, off, 64);
      float m0 = a0, m1 = a1, m2 = a2, m3 = a3;
      int   n0 = j0, n1 = j1, n2 = j2, n3 = j3;
      if (lexlt(b3, k3, m0, n0)) { m0 = b3; n0 = k3; }
      if (lexlt(b2, k2, m1, n1)) { m1 = b2; n1 = k2; }
      if (lexlt(b1, k1, m2, n2)) { m2 = b1; n2 = k1; }
      if (lexlt(b0, k0, m3, n3)) { m3 = b0; n3 = k0; }
      CE(m0, n0, m2, n2); CE(m1, n1, m3, n3);
      CE(m0, n0, m1, n1); CE(m2, n2, m3, n3);
      a0 = m0; a1 = m1; a2 = m2; a3 = m3;
      j0 = n0; j1 = n1; j2 = n2; j3 = n3;
    }
    if (lane == 0) {
      s_ci[0] = j0; s_ci[1] = j1; s_ci[2] = j2; s_ci[3] = j3;
      s_need = (a1 - a0 < DELTA) ? 1 : 0;
    }
  }
  __syncthreads();

  const int need = s_need;
  const float2 xv = *(const float2*)(x + (size_t)row * D + tid * 2);

  // phase 2: fp64 rescore of the 4 candidates (block-uniform branch)
  if (need) {
    const float2 qa = *(const float2*)(imp + (size_t)s_ci[0] * D + tid * 2);
    const float2 qb = *(const float2*)(imp + (size_t)s_ci[1] * D + tid * 2);
    const float2 qc = *(const float2*)(imp + (size_t)s_ci[2] * D + tid * 2);
    const float2 qd = *(const float2*)(imp + (size_t)s_ci[3] * D + tid * 2);
    double da, db, dc2, dd2;
    {
      double e0 = (double)xv.x - (double)qa.x, e1 = (double)xv.y - (double)qa.y;
      da = e0 * e0 + e1 * e1;
      e0 = (double)xv.x - (double)qb.x; e1 = (double)xv.y - (double)qb.y;
      db = e0 * e0 + e1 * e1;
      e0 = (double)xv.x - (double)qc.x; e1 = (double)xv.y - (double)qc.y;
      dc2 = e0 * e0 + e1 * e1;
      e0 = (double)xv.x - (double)qd.x; e1 = (double)xv.y - (double)qd.y;
      dd2 = e0 * e0 + e1 * e1;
    }
#pragma unroll
    for (int m = 1; m < 64; m <<= 1) {
      da  += __shfl_xor(da, m, 64);
      db  += __shfl_xor(db, m, 64);
      dc2 += __shfl_xor(dc2, m, 64);
      dd2 += __shfl_xor(dd2, m, 64);
    }
    if (lane == 0) {
      dred[wid][0] = da; dred[wid][1] = db; dred[wid][2] = dc2; dred[wid][3] = dd2;
    }
  }
  __syncthreads();
  if (tid == 0) {
    int bi = s_ci[0];
    if (need) {
      const double da = ((dred[0][0] + dred[1][0]) + (dred[2][0] + dred[3][0]));
      const double db = ((dred[0][1] + dred[1][1]) + (dred[2][1] + dred[3][1]));
      const double dc2 = ((dred[0][2] + dred[1][2]) + (dred[2][2] + dred[3][2]));
      const double dd2 = ((dred[0][3] + dred[1][3]) + (dred[2][3] + dred[3][3]));
      double bd = da; int bj = s_ci[0];
      if (db  < bd || (db  == bd && s_ci[1] < bj)) { bd = db;  bj = s_ci[1]; }
      if (dc2 < bd || (dc2 == bd && s_ci[2] < bj)) { bd = dc2; bj = s_ci[2]; }
      if (dd2 < bd || (dd2 == bd && s_ci[3] < bj)) { bd = dd2; bj = s_ci[3]; }
      bi = bj;
    }
    s_bi = bi;
  }
  __syncthreads();
  const int bi = s_bi;

  // phase 3: rotation trick + commit partials
  const float2 qv = *(const float2*)(imp + (size_t)bi * D + tid * 2);

  float4 p;
  p.x = fmaf(xv.x, xv.x, xv.y * xv.y);
  p.y = fmaf(qv.x, qv.x, qv.y * qv.y);
  p.z = fmaf(xv.x, qv.x, xv.y * qv.y);
  const float d0 = xv.x - qv.x + 1e-6f;
  const float d1 = xv.y - qv.y + 1e-6f;
  p.w = fmaf(d0, d0, d1 * d1);

#pragma unroll
  for (int m = 1; m < 64; m <<= 1) {
    p.x += __shfl_xor(p.x, m, 64);
    p.y += __shfl_xor(p.y, m, 64);
    p.z += __shfl_xor(p.z, m, 64);
    p.w += __shfl_xor(p.w, m, 64);
  }
  if (lane == 0) wsum[wid] = p;
  __syncthreads();
  const float sx2 = ((wsum[0].x + wsum[1].x) + (wsum[2].x + wsum[3].x));
  const float sq2 = ((wsum[0].y + wsum[1].y) + (wsum[2].y + wsum[3].y));
  const float sxq = ((wsum[0].z + wsum[1].z) + (wsum[2].z + wsum[3].z));
  const float scm = ((wsum[0].w + wsum[1].w) + (wsum[2].w + wsum[3].w));

  const float norm_x = sqrtf(sx2), norm_q = sqrtf(sq2);
  const float cnx = fmaxf(norm_x, 1e-6f), cnq = fmaxf(norm_q, 1e-6f);
  const float inx = 1.0f / cnx, inq = 1.0f / cnq;
  const float nuq2 = sx2 * inx * inx + 2.0f * sxq * inx * inq + sq2 * inq * inq;
  const float iw = 1.0f / fmaxf(sqrtf(nuq2), 1e-12f);
  const float e_dot_u = sx2 * inx;
  const float e_dot_w = (sx2 * inx + sxq * inq) * iw;
  const float scale = norm_q * inx;

  const float w0 = (xv.x * inx + qv.x * inq) * iw;
  const float w1 = (xv.y * inx + qv.y * inq) * iw;
  float r0 = xv.x - 2.0f * e_dot_w * w0;
  float r1 = xv.y - 2.0f * e_dot_w * w1;
  r0 = fmaf(2.0f * e_dot_u, qv.x * inq, r0);
  r1 = fmaf(2.0f * e_dot_u, qv.y * inq, r1);

  float* op = out + (size_t)row * D + tid * 2;
  op[0] = r0 * scale;
  op[1] = r1 * scale;

  if (tid == 0) {
    atomicAdd(commit_acc, scm);
    out[(size_t)NR * D + row] = (float)bi;
  }
}
#undef CE

// ---------------- K4: finalize commit loss ----------------
__global__ void k_final(const float* __restrict__ commit_acc,
                        float* __restrict__ out) {
  out[(size_t)NR * D + NR] = *commit_acc * (1.0f / (float)NR);
}

extern "C" void kernel_launch(void* const* d_in, const int* in_sizes, int n_in,
                              void* d_out, int out_size, void* d_ws, size_t ws_size,
                              hipStream_t stream) {
  const float* x  = (const float*)d_in[0];
  const float* cb = (const float*)d_in[1];
  const float* W  = (const float*)d_in[2];
  float* out = (float*)d_out;

  float* ws     = (float*)d_ws;
  float*  imp    = ws;                                   // C*D f32      (8 MB)
  float*  qnorm2 = imp + (size_t)C * D;                  // C            (16 KB)
  float2* t2v    = (float2*)(qnorm2 + C);                // NR*NSL       (8 MB)
  int2*   t2i    = (int2*)(t2v + (size_t)NR * NSL);      // NR*NSL       (8 MB)
  float*  commit = (float*)(t2i + (size_t)NR * NSL);     // 4
  ushort_t* ih   = (ushort_t*)(commit + 4);              // C*D bf16     (4 MB)

  // xh scratch in d_out's quantized region (16 MB), overwritten by k_rot
  ushort_t* xh = (ushort_t*)out;                         // NR*D bf16

  hipMemsetAsync(qnorm2, 0, C * sizeof(float), stream);
  hipMemsetAsync(commit, 0, 4 * sizeof(float), stream);

  k_implicit<<<dim3(C / 64, D / 64), 256, 0, stream>>>(cb, W, imp, qnorm2, ih);
  k_cvt<<<(NR * D) / (256 * 4), 256, 0, stream>>>(x, xh);
  k_dist<<<dim3(NR / 128, C / 512), 256, 0, stream>>>(xh, ih, qnorm2, t2v, t2i);
  k_rot<<<NR, 256, 0, stream>>>(x, imp, t2v, t2i, out, commit);
  k_final<<<1, 1, 0, stream>>>(commit, out);
}

// Round 11
// 577.332 us; speedup vs baseline: 1.0668x; 1.0668x over previous
//
#include <hip/hip_runtime.h>
#include <hip/hip_bf16.h>

// SimVQ: x[8,2048,512] f32, codebook[4096,512] f32, W[512,512] f32
// out (f32 flat): quantized_out[16384*512] | indices[16384] (as f32) | commit_loss[1]
//
// Round 11: m97-conformant k_dist staging. BK=64 so each tile-row slice is
// 128 B = one full cache line (8 lanes x 16 B contiguous per row per
// global_load_lds) -- r5..r10 staged 64-B half-lines (16 scattered segments
// per instruction, every line fetched twice). Bank swizzle for 128-B row
// stride: chunk_phys = chunk_log ^ (row&7) (spreads 64 lanes over all 8
// bank-quads = b128 floor). XCD-aware grid swizzle: each XCD owns 16
// A-panels, walks B inside its own L2. 1-leg bf16 + top-4 fp64 rescue kept.

typedef unsigned short ushort_t;
typedef __attribute__((ext_vector_type(8))) short bf16x8;
typedef __attribute__((ext_vector_type(4))) float f32x4;

constexpr int D  = 512;
constexpr int C  = 4096;
constexpr int NR = 16384;
constexpr int NSL = 64;             // partial slices per row (row-major)
constexpr float DELTA = 1.0f;       // top-4 fp64 rescue threshold (~12 sigma)

__device__ __forceinline__ ushort_t f2bf(float v) {
  __hip_bfloat16 h = __float2bfloat16(v);
  return *reinterpret_cast<ushort_t*>(&h);
}

__device__ __forceinline__ void gld16(void* lds, const void* g) {
  __builtin_amdgcn_global_load_lds(
      (const __attribute__((address_space(1))) unsigned int*)g,
      (__attribute__((address_space(3))) unsigned int*)lds, 16, 0, 0);
}

__device__ __forceinline__ bool lexlt(float v, int i, float ov, int oi) {
  return v < ov || (v == ov && i < oi);
}

__device__ __forceinline__ void top2_merge(float& v1, int& i1, float& v2, int& i2,
                                           float ov1, int oi1, float ov2, int oi2) {
  if (lexlt(ov1, oi1, v1, i1)) {
    float nv2; int ni2;
    if (lexlt(v1, i1, ov2, oi2)) { nv2 = v1; ni2 = i1; }
    else { nv2 = ov2; ni2 = oi2; }
    v2 = nv2; i2 = ni2; v1 = ov1; i1 = oi1;
  } else {
    if (lexlt(ov1, oi1, v2, i2)) { v2 = ov1; i2 = oi1; }
  }
}

// ---------------- K1: implicit = codebook @ W^T, fused qnorm2 + bf16 hi ----------------
__global__ __launch_bounds__(256) void k_implicit(
    const float* __restrict__ cb, const float* __restrict__ W,
    float* __restrict__ imp, float* __restrict__ qnorm2,
    ushort_t* __restrict__ ih) {
  __shared__ float As[16][65];
  __shared__ float Bs[16][65];
  const int c0 = blockIdx.x * 64;
  const int j0 = blockIdx.y * 64;
  const int tid = threadIdx.x;
  const int tr = tid >> 4, tc = tid & 15;
  const int lm = tid >> 2;
  const int lq = (tid & 3) << 2;
  float acc[4][4] = {{0.f}};
  for (int kk = 0; kk < D; kk += 16) {
    __syncthreads();
    float4 av = *(const float4*)(cb + (size_t)(c0 + lm) * D + kk + lq);
    float4 bv = *(const float4*)(W  + (size_t)(j0 + lm) * D + kk + lq);
    As[lq + 0][lm] = av.x; As[lq + 1][lm] = av.y; As[lq + 2][lm] = av.z; As[lq + 3][lm] = av.w;
    Bs[lq + 0][lm] = bv.x; Bs[lq + 1][lm] = bv.y; Bs[lq + 2][lm] = bv.z; Bs[lq + 3][lm] = bv.w;
    __syncthreads();
#pragma unroll
    for (int k = 0; k < 16; ++k) {
      float a[4], b[4];
#pragma unroll
      for (int i = 0; i < 4; ++i) a[i] = As[k][tr * 4 + i];
#pragma unroll
      for (int j = 0; j < 4; ++j) b[j] = Bs[k][tc * 4 + j];
#pragma unroll
      for (int i = 0; i < 4; ++i)
#pragma unroll
        for (int j = 0; j < 4; ++j) acc[i][j] = fmaf(a[i], b[j], acc[i][j]);
    }
  }
#pragma unroll
  for (int i = 0; i < 4; ++i) {
    const int row = c0 + tr * 4 + i;
    float sq = 0.f;
#pragma unroll
    for (int j = 0; j < 4; ++j) {
      const float v = acc[i][j];
      const size_t off = (size_t)row * D + j0 + tc * 4 + j;
      imp[off] = v;
      ih[off] = f2bf(v);
      sq = fmaf(v, v, sq);
    }
#pragma unroll
    for (int m = 1; m < 16; m <<= 1) sq += __shfl_xor(sq, m, 64);
    if (tc == 0) atomicAdd(&qnorm2[row], sq);
  }
}

// ---------------- K1b: x -> xh bf16 ----------------
__global__ __launch_bounds__(256) void k_cvt(const float* __restrict__ x,
                                             ushort_t* __restrict__ xh) {
  const size_t i = ((size_t)blockIdx.x * 256 + threadIdx.x) * 4;
  float4 v = *(const float4*)(x + i);
  ushort4 h;
  h.x = f2bf(v.x); h.y = f2bf(v.y); h.z = f2bf(v.z); h.w = f2bf(v.w);
  *(ushort4*)(xh + i) = h;
}

// ---------------- K2: 1-leg MFMA distance + fused TOP-2 argmin ----------------
// 1-D grid 4096, XCD-swizzled -> (bx row-block 0..127, by col-block 0..31).
// 256 threads (4 waves 2x2). Tile 128x128, BK=64 (full-cache-line staging),
// single-buffer 32 KB LDS, chunk^=(row&7) swizzle.
__global__ __launch_bounds__(256, 4) void k_dist(
    const ushort_t* __restrict__ xh, const ushort_t* __restrict__ ih,
    const float* __restrict__ qnorm2,
    float2* __restrict__ t2v, int2* __restrict__ t2i) {
  __shared__ ushort_t Ah[128 * 64], Bh[128 * 64];   // 16 KB each
  const int id = blockIdx.x;
  const int bx = ((id >> 8) << 3) + (id & 7);   // row-block: XCD = id&7 owns 16 panels
  const int by = (id >> 3) & 31;                // col-block
  const int r0 = bx * 128;
  const int c0 = by * 128;
  const int t = threadIdx.x;
  const int wid = t >> 6, lane = t & 63;
  const int wr = wid >> 1, wc = wid & 1;

  // staging: thread t -> row (t>>3)+32j, phys chunk t&7 (16 B), source chunk
  // pre-swizzled: chunk_log = (t&7) ^ ((t>>3)&7); full 128-B line per 8 lanes.
  const int koff = (((t & 7) ^ ((t >> 3) & 7)) << 3);   // elems
  const size_t gA0 = (size_t)(r0 + (t >> 3)) * D + koff;
  const size_t gB0 = (size_t)(c0 + (t >> 3)) * D + koff;
  char* lA = (char*)Ah + wid * 1024;   // wave-uniform base
  char* lB = (char*)Bh + wid * 1024;

  f32x4 acc[4][4];
#pragma unroll
  for (int m = 0; m < 4; ++m)
#pragma unroll
    for (int n = 0; n < 4; ++n) acc[m][n] = (f32x4){0.f, 0.f, 0.f, 0.f};

  // fragment reads: row = base16 + (lane&15); row&7 = lane&7.
  // ks=0: chunk_phys = (lane>>4) ^ (lane&7); ks=1: ^4  (byte XOR 64)
  const int arow = wr * 64 + (lane & 15);
  const int brow = wc * 64 + (lane & 15);
  const int cp0 = (((lane >> 4) ^ (lane & 7)) << 4);    // bytes

  for (int kk = 0; kk < D; kk += 64) {
    __syncthreads();
#pragma unroll
    for (int j = 0; j < 4; ++j) {
      gld16(lA + j * 4096, xh + gA0 + kk + (size_t)(32 * j) * D);
      gld16(lB + j * 4096, ih + gB0 + kk + (size_t)(32 * j) * D);
    }
    __syncthreads();   // drains vmcnt(0) -> tiles ready

#pragma unroll
    for (int ks = 0; ks < 2; ++ks) {
      const int kx = cp0 ^ (ks << 6);
      bf16x8 a[4], b[4];
#pragma unroll
      for (int m = 0; m < 4; ++m)
        a[m] = *(const bf16x8*)((const char*)Ah + ((arow + m * 16) << 7) + kx);
#pragma unroll
      for (int n = 0; n < 4; ++n)
        b[n] = *(const bf16x8*)((const char*)Bh + ((brow + n * 16) << 7) + kx);
#pragma unroll
      for (int m = 0; m < 4; ++m)
#pragma unroll
        for (int n = 0; n < 4; ++n)
          acc[m][n] = __builtin_amdgcn_mfma_f32_16x16x32_bf16(a[m], b[n], acc[m][n], 0, 0, 0);
    }
  }

  // epilogue: score = qn[c] - 2*dot ; per-row TOP-2 over THIS WAVE's 64 cols.
  // Unique writer per (row, slice): slice = by*2 + wc; t2 row-major [row][64].
  int colg[4]; float qnv[4];
#pragma unroll
  for (int n = 0; n < 4; ++n) {
    colg[n] = c0 + wc * 64 + n * 16 + (lane & 15);
    qnv[n] = qnorm2[colg[n]];
  }
  const int sp2 = by * 2 + wc;
#pragma unroll
  for (int m = 0; m < 4; ++m)
#pragma unroll
    for (int r = 0; r < 4; ++r) {
      float v1 = fmaf(-2.f, acc[m][0][r], qnv[0]); int i1 = colg[0];
      float v2 = 3.4e38f;                          int i2 = 0x7fffffff;
#pragma unroll
      for (int n = 1; n < 4; ++n) {
        const float s = fmaf(-2.f, acc[m][n][r], qnv[n]);
        const int   c = colg[n];
        if (lexlt(s, c, v1, i1)) { v2 = v1; i2 = i1; v1 = s; i1 = c; }
        else if (lexlt(s, c, v2, i2)) { v2 = s; i2 = c; }
      }
#pragma unroll
      for (int off = 1; off < 16; off <<= 1) {
        const float ov1 = __shfl_xor(v1, off, 64);
        const int   oi1 = __shfl_xor(i1, off, 64);
        const float ov2 = __shfl_xor(v2, off, 64);
        const int   oi2 = __shfl_xor(i2, off, 64);
        top2_merge(v1, i1, v2, i2, ov1, oi1, ov2, oi2);
      }
      if ((lane & 15) == 0) {
        const int row = r0 + wr * 64 + m * 16 + (lane >> 4) * 4 + r;
        t2v[(size_t)row * NSL + sp2] = make_float2(v1, v2);
        t2i[(size_t)row * NSL + sp2] = make_int2(i1, i2);
      }
    }
}

// compare-exchange ascending (lex) on named scalars
#define CE(vx, ix, vy, iy)                                        \
  do {                                                            \
    if (lexlt(vy, iy, vx, ix)) {                                  \
      float tv = vx; int ti = ix;                                 \
      vx = vy; ix = iy; vy = tv; iy = ti;                         \
    }                                                             \
  } while (0)

// ---------------- K3: top-4 merge + fp64 rescore + rotation ----------------
__global__ __launch_bounds__(256) void k_rot(
    const float* __restrict__ x, const float* __restrict__ imp,
    const float2* __restrict__ t2v, const int2* __restrict__ t2i,
    float* __restrict__ out, float* __restrict__ commit_acc) {
  const int row = blockIdx.x;
  const int tid = threadIdx.x;
  const int wid = tid >> 6, lane = tid & 63;

  __shared__ int s_ci[4];
  __shared__ int s_need, s_bi;
  __shared__ double dred[4][4];
  __shared__ float4 wsum[4];

  // phase 1: wave 0 merges the 64 per-slice top-2 into a global TOP-4
  if (wid == 0) {
    const float2 vv = t2v[(size_t)row * NSL + lane];   // coalesced row-major
    const int2   ii = t2i[(size_t)row * NSL + lane];
    float a0 = vv.x, a1 = vv.y, a2 = 3.4e38f, a3 = 3.4e38f;
    int   j0 = ii.x, j1 = ii.y, j2 = 0x7fffffff, j3 = 0x7fffffff;
#pragma unroll
    for (int off = 1; off < 64; off <<= 1) {
      const float b0 = __shfl_xor(a0, off, 64), b1 = __shfl_xor(a1, off, 64);
      const float b2 = __shfl_xor(a2, off, 64), b3 = __shfl_xor(a3, off, 64);
      const int   k0 = __shfl_xor(j0, off, 64), k1 = __shfl_xor(j1, off, 64);
      const int   k2 = __shfl_xor(j2, off, 64), k3 = __shfl_xor(j3, off, 64);
      float m0 = a0, m1 = a1, m2 = a2, m3 = a3;
      int   n0 = j0, n1 = j1, n2 = j2, n3 = j3;
      if (lexlt(b3, k3, m0, n0)) { m0 = b3; n0 = k3; }
      if (lexlt(b2, k2, m1, n1)) { m1 = b2; n1 = k2; }
      if (lexlt(b1, k1, m2, n2)) { m2 = b1; n2 = k1; }
      if (lexlt(b0, k0, m3, n3)) { m3 = b0; n3 = k0; }
      CE(m0, n0, m2, n2); CE(m1, n1, m3, n3);
      CE(m0, n0, m1, n1); CE(m2, n2, m3, n3);
      a0 = m0; a1 = m1; a2 = m2; a3 = m3;
      j0 = n0; j1 = n1; j2 = n2; j3 = n3;
    }
    if (lane == 0) {
      s_ci[0] = j0; s_ci[1] = j1; s_ci[2] = j2; s_ci[3] = j3;
      s_need = (a1 - a0 < DELTA) ? 1 : 0;
    }
  }
  __syncthreads();

  const int need = s_need;
  const float2 xv = *(const float2*)(x + (size_t)row * D + tid * 2);

  // phase 2: fp64 rescore of the 4 candidates (block-uniform branch)
  if (need) {
    const float2 qa = *(const float2*)(imp + (size_t)s_ci[0] * D + tid * 2);
    const float2 qb = *(const float2*)(imp + (size_t)s_ci[1] * D + tid * 2);
    const float2 qc = *(const float2*)(imp + (size_t)s_ci[2] * D + tid * 2);
    const float2 qd = *(const float2*)(imp + (size_t)s_ci[3] * D + tid * 2);
    double da, db, dc2, dd2;
    {
      double e0 = (double)xv.x - (double)qa.x, e1 = (double)xv.y - (double)qa.y;
      da = e0 * e0 + e1 * e1;
      e0 = (double)xv.x - (double)qb.x; e1 = (double)xv.y - (double)qb.y;
      db = e0 * e0 + e1 * e1;
      e0 = (double)xv.x - (double)qc.x; e1 = (double)xv.y - (double)qc.y;
      dc2 = e0 * e0 + e1 * e1;
      e0 = (double)xv.x - (double)qd.x; e1 = (double)xv.y - (double)qd.y;
      dd2 = e0 * e0 + e1 * e1;
    }
#pragma unroll
    for (int m = 1; m < 64; m <<= 1) {
      da  += __shfl_xor(da, m, 64);
      db  += __shfl_xor(db, m, 64);
      dc2 += __shfl_xor(dc2, m, 64);
      dd2 += __shfl_xor(dd2, m, 64);
    }
    if (lane == 0) {
      dred[wid][0] = da; dred[wid][1] = db; dred[wid][2] = dc2; dred[wid][3] = dd2;
    }
  }
  __syncthreads();
  if (tid == 0) {
    int bi = s_ci[0];
    if (need) {
      const double da = ((dred[0][0] + dred[1][0]) + (dred[2][0] + dred[3][0]));
      const double db = ((dred[0][1] + dred[1][1]) + (dred[2][1] + dred[3][1]));
      const double dc2 = ((dred[0][2] + dred[1][2]) + (dred[2][2] + dred[3][2]));
      const double dd2 = ((dred[0][3] + dred[1][3]) + (dred[2][3] + dred[3][3]));
      double bd = da; int bj = s_ci[0];
      if (db  < bd || (db  == bd && s_ci[1] < bj)) { bd = db;  bj = s_ci[1]; }
      if (dc2 < bd || (dc2 == bd && s_ci[2] < bj)) { bd = dc2; bj = s_ci[2]; }
      if (dd2 < bd || (dd2 == bd && s_ci[3] < bj)) { bd = dd2; bj = s_ci[3]; }
      bi = bj;
    }
    s_bi = bi;
  }
  __syncthreads();
  const int bi = s_bi;

  // phase 3: rotation trick + commit partials
  const float2 qv = *(const float2*)(imp + (size_t)bi * D + tid * 2);

  float4 p;
  p.x = fmaf(xv.x, xv.x, xv.y * xv.y);
  p.y = fmaf(qv.x, qv.x, qv.y * qv.y);
  p.z = fmaf(xv.x, qv.x, xv.y * qv.y);
  const float d0 = xv.x - qv.x + 1e-6f;
  const float d1 = xv.y - qv.y + 1e-6f;
  p.w = fmaf(d0, d0, d1 * d1);

#pragma unroll
  for (int m = 1; m < 64; m <<= 1) {
    p.x += __shfl_xor(p.x, m, 64);
    p.y += __shfl_xor(p.y, m, 64);
    p.z += __shfl_xor(p.z, m, 64);
    p.w += __shfl_xor(p.w, m, 64);
  }
  if (lane == 0) wsum[wid] = p;
  __syncthreads();
  const float sx2 = ((wsum[0].x + wsum[1].x) + (wsum[2].x + wsum[3].x));
  const float sq2 = ((wsum[0].y + wsum[1].y) + (wsum[2].y + wsum[3].y));
  const float sxq = ((wsum[0].z + wsum[1].z) + (wsum[2].z + wsum[3].z));
  const float scm = ((wsum[0].w + wsum[1].w) + (wsum[2].w + wsum[3].w));

  const float norm_x = sqrtf(sx2), norm_q = sqrtf(sq2);
  const float cnx = fmaxf(norm_x, 1e-6f), cnq = fmaxf(norm_q, 1e-6f);
  const float inx = 1.0f / cnx, inq = 1.0f / cnq;
  const float nuq2 = sx2 * inx * inx + 2.0f * sxq * inx * inq + sq2 * inq * inq;
  const float iw = 1.0f / fmaxf(sqrtf(nuq2), 1e-12f);
  const float e_dot_u = sx2 * inx;
  const float e_dot_w = (sx2 * inx + sxq * inq) * iw;
  const float scale = norm_q * inx;

  const float w0 = (xv.x * inx + qv.x * inq) * iw;
  const float w1 = (xv.y * inx + qv.y * inq) * iw;
  float r0 = xv.x - 2.0f * e_dot_w * w0;
  float r1 = xv.y - 2.0f * e_dot_w * w1;
  r0 = fmaf(2.0f * e_dot_u, qv.x * inq, r0);
  r1 = fmaf(2.0f * e_dot_u, qv.y * inq, r1);

  float* op = out + (size_t)row * D + tid * 2;
  op[0] = r0 * scale;
  op[1] = r1 * scale;

  if (tid == 0) {
    atomicAdd(commit_acc, scm);
    out[(size_t)NR * D + row] = (float)bi;
  }
}
#undef CE

// ---------------- K4: finalize commit loss ----------------
__global__ void k_final(const float* __restrict__ commit_acc,
                        float* __restrict__ out) {
  out[(size_t)NR * D + NR] = *commit_acc * (1.0f / (float)NR);
}

extern "C" void kernel_launch(void* const* d_in, const int* in_sizes, int n_in,
                              void* d_out, int out_size, void* d_ws, size_t ws_size,
                              hipStream_t stream) {
  const float* x  = (const float*)d_in[0];
  const float* cb = (const float*)d_in[1];
  const float* W  = (const float*)d_in[2];
  float* out = (float*)d_out;

  float* ws     = (float*)d_ws;
  float*  imp    = ws;                                   // C*D f32      (8 MB)
  float*  qnorm2 = imp + (size_t)C * D;                  // C            (16 KB)
  float2* t2v    = (float2*)(qnorm2 + C);                // NR*NSL       (8 MB)
  int2*   t2i    = (int2*)(t2v + (size_t)NR * NSL);      // NR*NSL       (8 MB)
  float*  commit = (float*)(t2i + (size_t)NR * NSL);     // 4
  ushort_t* ih   = (ushort_t*)(commit + 4);              // C*D bf16     (4 MB)

  // xh scratch in d_out's quantized region (16 MB), overwritten by k_rot
  ushort_t* xh = (ushort_t*)out;                         // NR*D bf16

  hipMemsetAsync(qnorm2, 0, C * sizeof(float), stream);
  hipMemsetAsync(commit, 0, 4 * sizeof(float), stream);

  k_implicit<<<dim3(C / 64, D / 64), 256, 0, stream>>>(cb, W, imp, qnorm2, ih);
  k_cvt<<<(NR * D) / (256 * 4), 256, 0, stream>>>(x, xh);
  k_dist<<<4096, 256, 0, stream>>>(xh, ih, qnorm2, t2v, t2i);
  k_rot<<<NR, 256, 0, stream>>>(x, imp, t2v, t2i, out, commit);
  k_final<<<1, 1, 0, stream>>>(commit, out);
}